// Round 4
// baseline (115.364 us; speedup 1.0000x reference)
//
#include <hip/hip_runtime.h>
#include <math.h>

#define B_ 4
#define C_ 32
#define D_ 16
#define H_ 128
#define W_ 128
#define HW_ (H_*W_)
#define SP_ (D_*HW_)

typedef float f32x4 __attribute__((ext_vector_type(4)));

__device__ __forceinline__ int refl(int i, int n) {
    i = (i < 0) ? -i : i;
    i = (i >= n) ? (2*n - 2 - i) : i;
    return i;
}

// Pass 0: combined stencil Wc[ci][od][oh][ow] (2x7x7x5)
__global__ void prep_weights_kernel(const float* __restrict__ w1,
                                    const float* __restrict__ w2,
                                    const float* __restrict__ w3,
                                    const float* __restrict__ wf,
                                    float* __restrict__ Wc) {
    int t = blockIdx.x * blockDim.x + threadIdx.x;
    if (t >= 2*7*7*5) return;
    int ow = t % 5;
    int oh = (t / 5) % 7;
    int od = (t / 35) % 7;
    int ci = t / 245;
    float v = wf[0] * w1[((ci*7+od)*7+oh)*5+ow];
    if (od>=1 && od<=5 && oh>=1 && oh<=5 && ow>=1 && ow<=3)
        v = fmaf(wf[1], w2[((ci*5+(od-1))*5+(oh-1))*3+(ow-1)], v);
    if (od>=2 && od<=4 && oh>=2 && oh<=4 && ow==2)
        v = fmaf(wf[2], w3[(ci*3+(od-2))*3+(ow==2?(oh-2):0)], v);
    Wc[t] = v;
}

// Pass 1: channel pool -> s[b][0]=mean, s[b][1]=max, layout [B][2][D][H][W]
__global__ __launch_bounds__(256) void pool_kernel(const float* __restrict__ x,
                                                   float* __restrict__ s) {
    int t = blockIdx.x * blockDim.x + threadIdx.x;
    if (t >= B_*D_*H_*(W_/4)) return;
    int w4 = (t % (W_/4)) * 4;
    int rest = t / (W_/4);
    int h = rest % H_;
    int bd = rest / H_;
    int d = bd % D_;
    int b = bd / D_;
    const float* xp = x + (b*C_*D_ + d)*HW_ + h*W_ + w4;
    f32x4 v = *(const f32x4*)xp;
    f32x4 sm = v, mx = v;
    #pragma unroll 8
    for (int c = 1; c < C_; ++c) {
        f32x4 u = *(const f32x4*)(xp + c*SP_);
        sm += u;
        mx.x=fmaxf(mx.x,u.x); mx.y=fmaxf(mx.y,u.y); mx.z=fmaxf(mx.z,u.z); mx.w=fmaxf(mx.w,u.w);
    }
    sm *= (1.0f/32.0f);
    *(f32x4*)(s + ((b*2+0)*D_ + d)*HW_ + h*W_ + w4) = sm;
    *(f32x4*)(s + ((b*2+1)*D_ + d)*HW_ + h*W_ + w4) = mx;
}

// Pass 2: combined 2x7x7x5 stencil over s -> sigmoid weight map sg [B][D][H][W].
// Thread: 1 d, 1 h, 4 w. Block 256 = 32 w-tiles x 8 h. Grid B*D*(H/8) = 1024.
// Each stencil row: two 16B loads (L @ w0-2, R @ w0+2) cover all 8 taps; edge
// lanes reload aligned and remap via reflection (no shuffles, no LDS).
__global__ __launch_bounds__(256) void stencil_kernel(
        const float* __restrict__ s,
        const float* __restrict__ Wc,
        float* __restrict__ sg) {
    int bid = blockIdx.x;
    int ht = bid & 15;
    int d0 = (bid >> 4) & 15;
    int b  = bid >> 8;
    int t = threadIdx.x;
    int w0 = (t & 31) * 4;
    int h0 = ht * 8 + (t >> 5);

    const bool le = (t & 31) == 0;    // w0 == 0
    const bool re = (t & 31) == 31;   // w0 == 124
    const int offL = le ? 0 : -2;
    const int offR = re ? 0 :  2;

    int drow[7];
    #pragma unroll
    for (int od = 0; od < 7; ++od) drow[od] = refl(d0 + od - 3, D_) * HW_;

    float acc[4] = {0.f, 0.f, 0.f, 0.f};

    for (int ci = 0; ci < 2; ++ci) {
        const float* sc = s + (b*2 + ci)*SP_;
        const float* wcb_ci = Wc + ci*245;
        for (int oh = 0; oh < 7; ++oh) {
            const float* sh = sc + refl(h0 + oh - 3, H_)*W_ + w0;
            const float* wcb = wcb_ci + oh*5;
            #pragma unroll
            for (int od = 0; od < 7; ++od) {
                const float* rp = sh + drow[od];
                const f32x4 L = *(const f32x4*)(rp + offL);
                const f32x4 R = *(const f32x4*)(rp + offR);
                float v[8];
                v[0] = le ? L.z : L.x;   // w0-2 (refl(-2)=2)
                v[1] = L.y;              // w0-1 (refl(-1)=1 == L.y in both cases)
                v[2] = le ? L.x : L.z;   // w0
                v[3] = le ? L.y : L.w;   // w0+1
                v[4] = re ? R.z : R.x;   // w0+2
                v[5] = re ? R.w : R.y;   // w0+3
                v[6] = R.z;              // w0+4 (refl(128)=126 == R.z in both cases)
                v[7] = re ? R.y : R.w;   // w0+5 (refl(129)=125)
                const float* wp = wcb + od*35;
                #pragma unroll
                for (int ow = 0; ow < 5; ++ow) {
                    float wgt = wp[ow];
                    #pragma unroll
                    for (int wi = 0; wi < 4; ++wi)
                        acc[wi] = fmaf(wgt, v[wi+ow], acc[wi]);
                }
            }
        }
    }

    f32x4 o;
    o.x = 1.0f/(1.0f + __expf(-acc[0]));
    o.y = 1.0f/(1.0f + __expf(-acc[1]));
    o.z = 1.0f/(1.0f + __expf(-acc[2]));
    o.w = 1.0f/(1.0f + __expf(-acc[3]));
    *(f32x4*)(sg + ((b*D_ + d0)*H_ + h0)*W_ + w0) = o;
}

// Pass 3: out = x * sg, pure streaming. Block = one (b,d,h) row across all C.
// Grid B*D*H = 8192. t: w4=(t&31)*4, c0=t>>5; 4 channel iterations.
__global__ __launch_bounds__(256) void mult_kernel(
        const float* __restrict__ x,
        const float* __restrict__ sg,
        float* __restrict__ out) {
    int bid = blockIdx.x;
    int h = bid & 127;
    int d = (bid >> 7) & 15;
    int b = bid >> 11;
    int t = threadIdx.x;
    int w4 = (t & 31) * 4;
    int c0 = t >> 5;

    f32x4 g = *(const f32x4*)(sg + ((b*D_ + d)*H_ + h)*W_ + w4);

    int base = (b*C_*D_ + d)*HW_ + h*W_ + w4;
    #pragma unroll
    for (int k = 0; k < 4; ++k) {
        int c = c0 + k*8;
        int i0 = base + c*SP_;
        f32x4 xv = *(const f32x4*)(x + i0);
        __builtin_nontemporal_store(xv * g, (f32x4*)(out + i0));
    }
}

extern "C" void kernel_launch(void* const* d_in, const int* in_sizes, int n_in,
                              void* d_out, int out_size, void* d_ws, size_t ws_size,
                              hipStream_t stream) {
    const float* x  = (const float*)d_in[0];
    const float* w1 = (const float*)d_in[1];
    const float* w2 = (const float*)d_in[2];
    const float* w3 = (const float*)d_in[3];
    const float* wf = (const float*)d_in[4];
    float* out = (float*)d_out;
    float* Wc = (float*)d_ws;                       // 512 floats
    float* s  = (float*)d_ws + 512;                 // [B][2][D][H][W] = 8 MB
    float* sg = s + B_*2*SP_;                       // [B][D][H][W] = 4 MB

    prep_weights_kernel<<<1, 512, 0, stream>>>(w1, w2, w3, wf, Wc);
    pool_kernel<<<(B_*D_*H_*(W_/4) + 255)/256, 256, 0, stream>>>(x, s);
    stencil_kernel<<<B_*D_*(H_/8), 256, 0, stream>>>(s, Wc, sg);
    mult_kernel<<<B_*D_*H_, 256, 0, stream>>>(x, sg, out);
}

// Round 5
// 86.040 us; speedup vs baseline: 1.3408x; 1.3408x over previous
//
#include <hip/hip_runtime.h>
#include <math.h>

#define B_ 4
#define C_ 32
#define D_ 16
#define H_ 128
#define W_ 128
#define HW_ (H_*W_)
#define SP_ (D_*HW_)

typedef float f32x4 __attribute__((ext_vector_type(4)));
typedef float f32x4u __attribute__((ext_vector_type(4), aligned(4)));

__device__ __forceinline__ int refl(int i, int n) {
    i = (i < 0) ? -i : i;
    i = (i >= n) ? (2*n - 2 - i) : i;
    return i;
}

// Pass 0: combined stencil Wc[ci][od][oh][ow] (2x7x7x5)
__global__ void prep_weights_kernel(const float* __restrict__ w1,
                                    const float* __restrict__ w2,
                                    const float* __restrict__ w3,
                                    const float* __restrict__ wf,
                                    float* __restrict__ Wc) {
    int t = blockIdx.x * blockDim.x + threadIdx.x;
    if (t >= 2*7*7*5) return;
    int ow = t % 5;
    int oh = (t / 5) % 7;
    int od = (t / 35) % 7;
    int ci = t / 245;
    float v = wf[0] * w1[((ci*7+od)*7+oh)*5+ow];
    if (od>=1 && od<=5 && oh>=1 && oh<=5 && ow>=1 && ow<=3)
        v = fmaf(wf[1], w2[((ci*5+(od-1))*5+(oh-1))*3+(ow-1)], v);
    if (od>=2 && od<=4 && oh>=2 && oh<=4 && ow==2)
        v = fmaf(wf[2], w3[(ci*3+(od-2))*3+(oh-2)], v);
    Wc[t] = v;
}

// Pass 1: channel pool -> s[b][0]=mean, s[b][1]=max, layout [B][2][D][H][W]
__global__ __launch_bounds__(256) void pool_kernel(const float* __restrict__ x,
                                                   float* __restrict__ s) {
    int t = blockIdx.x * blockDim.x + threadIdx.x;
    if (t >= B_*D_*H_*(W_/4)) return;
    int w4 = (t % (W_/4)) * 4;
    int rest = t / (W_/4);
    int h = rest % H_;
    int bd = rest / H_;
    int d = bd % D_;
    int b = bd / D_;
    const float* xp = x + (b*C_*D_ + d)*HW_ + h*W_ + w4;
    f32x4 v = *(const f32x4*)xp;
    f32x4 sm = v, mx = v;
    #pragma unroll 8
    for (int c = 1; c < C_; ++c) {
        f32x4 u = *(const f32x4*)(xp + c*SP_);
        sm += u;
        mx.x=fmaxf(mx.x,u.x); mx.y=fmaxf(mx.y,u.y); mx.z=fmaxf(mx.z,u.z); mx.w=fmaxf(mx.w,u.w);
    }
    sm *= (1.0f/32.0f);
    *(f32x4*)(s + ((b*2+0)*D_ + d)*HW_ + h*W_ + w4) = sm;
    *(f32x4*)(s + ((b*2+1)*D_ + d)*HW_ + h*W_ + w4) = mx;
}

// Pass 2 (merged): combined 2x7x7x5 stencil + sigmoid + x-multiply.
// Thread tile: 2 d x 1 h x 4 w. Block 256 = 32 w-tiles x 8 h.
// Grid: B * (D/2) * (H/8) = 512 blocks (2 blocks/CU).
// Each (ci,oh,k) row: two 16B loads (L @ w0-2, R @ w0+2), shared across both
// d-outputs via the 8-plane tap union (k=0..7). No shuffles, no LDS.
__global__ __launch_bounds__(256, 2) void spatial_att_kernel(
        const float* __restrict__ x,
        const float* __restrict__ s,
        const float* __restrict__ Wc,
        float* __restrict__ out) {
    int bid = blockIdx.x;
    int ht = bid & 15;
    int dp = (bid >> 4) & 7;
    int b  = bid >> 7;
    int t = threadIdx.x;
    int w0 = (t & 31) * 4;
    int h0 = ht * 8 + (t >> 5);
    int d0 = dp * 2;

    const bool le = (t & 31) == 0;    // w0 == 0
    const bool re = (t & 31) == 31;   // w0 == 124
    const int offL = le ? 0 : -2;
    const int offR = re ? 0 :  2;

    // input d-planes for outputs d0 and d0+1: k = 0..7 -> d0 + k - 3 (reflected)
    int drow[8];
    #pragma unroll
    for (int k = 0; k < 8; ++k) drow[k] = refl(d0 + k - 3, D_) * HW_;

    float acc0[4] = {0.f, 0.f, 0.f, 0.f};
    float acc1[4] = {0.f, 0.f, 0.f, 0.f};

    for (int ci = 0; ci < 2; ++ci) {
        const float* sc = s + (b*2 + ci)*SP_;
        const float* wcb_ci = Wc + ci*245;
        for (int oh = 0; oh < 7; ++oh) {
            const float* sh = sc + refl(h0 + oh - 3, H_)*W_ + w0;
            const float* wcb = wcb_ci + oh*5;   // + od*35 + ow
            #pragma unroll
            for (int k = 0; k < 8; ++k) {
                const float* rp = sh + drow[k];
                const f32x4 L = *(const f32x4u*)(rp + offL);
                const f32x4 R = *(const f32x4u*)(rp + offR);
                float v[8];
                v[0] = le ? L.z : L.x;   // w0-2 (refl(-2)=2)
                v[1] = L.y;              // w0-1
                v[2] = le ? L.x : L.z;   // w0
                v[3] = le ? L.y : L.w;   // w0+1
                v[4] = re ? R.z : R.x;   // w0+2
                v[5] = re ? R.w : R.y;   // w0+3
                v[6] = R.z;              // w0+4 (refl(128)=126)
                v[7] = re ? R.y : R.w;   // w0+5 (refl(129)=125)
                // output d0: od index = k (valid k<=6)
                if (k <= 6) {
                    const float* wp = wcb + k*35;
                    #pragma unroll
                    for (int ow = 0; ow < 5; ++ow) {
                        float wgt = wp[ow];
                        #pragma unroll
                        for (int wi = 0; wi < 4; ++wi)
                            acc0[wi] = fmaf(wgt, v[wi+ow], acc0[wi]);
                    }
                }
                // output d0+1: od index = k-1 (valid k>=1)
                if (k >= 1) {
                    const float* wp = wcb + (k-1)*35;
                    #pragma unroll
                    for (int ow = 0; ow < 5; ++ow) {
                        float wgt = wp[ow];
                        #pragma unroll
                        for (int wi = 0; wi < 4; ++wi)
                            acc1[wi] = fmaf(wgt, v[wi+ow], acc1[wi]);
                    }
                }
            }
        }
    }

    float sg0[4], sg1[4];
    #pragma unroll
    for (int wi = 0; wi < 4; ++wi) {
        sg0[wi] = 1.0f/(1.0f + __expf(-acc0[wi]));
        sg1[wi] = 1.0f/(1.0f + __expf(-acc1[wi]));
    }

    int obase = (b*C_*D_ + d0)*HW_ + h0*W_ + w0;
    #pragma unroll 8
    for (int c = 0; c < C_; ++c) {
        int i0 = obase + c*SP_;
        f32x4 xv0 = *(const f32x4*)(x + i0);
        f32x4 xv1 = *(const f32x4*)(x + i0 + HW_);
        f32x4 o0; o0.x=xv0.x*sg0[0]; o0.y=xv0.y*sg0[1]; o0.z=xv0.z*sg0[2]; o0.w=xv0.w*sg0[3];
        f32x4 o1; o1.x=xv1.x*sg1[0]; o1.y=xv1.y*sg1[1]; o1.z=xv1.z*sg1[2]; o1.w=xv1.w*sg1[3];
        __builtin_nontemporal_store(o0, (f32x4*)(out + i0));
        __builtin_nontemporal_store(o1, (f32x4*)(out + i0 + HW_));
    }
}

extern "C" void kernel_launch(void* const* d_in, const int* in_sizes, int n_in,
                              void* d_out, int out_size, void* d_ws, size_t ws_size,
                              hipStream_t stream) {
    const float* x  = (const float*)d_in[0];
    const float* w1 = (const float*)d_in[1];
    const float* w2 = (const float*)d_in[2];
    const float* w3 = (const float*)d_in[3];
    const float* wf = (const float*)d_in[4];
    float* out = (float*)d_out;
    float* Wc = (float*)d_ws;            // 512 floats
    float* s  = (float*)d_ws + 512;      // [B][2][D][H][W] = 8 MB

    prep_weights_kernel<<<1, 512, 0, stream>>>(w1, w2, w3, wf, Wc);
    pool_kernel<<<(B_*D_*H_*(W_/4) + 255)/256, 256, 0, stream>>>(x, s);
    spatial_att_kernel<<<B_*(D_/2)*(H_/8), 256, 0, stream>>>(x, s, Wc, out);
}